// Round 6
// baseline (1026.838 us; speedup 1.0000x reference)
//
#include <hip/hip_runtime.h>

#define DEG 16
#define E12 12
#define MAX_ITERS 32
#define BLK 1024
#define NCH 8               // chunks (= buckets), COMPILE-TIME (full unroll)
#define KSLOT 5             // register slots per chunk per thread
#define SLOTS (NCH * KSLOT) // 40 register-resident edges per thread
#define LDSH 12544          // floats per LDS staging half (2 x 49 KB)
#define UST 4               // staging unroll (ceil(LDSH/4/1024))
#define JMAX 96             // legacy ws-layout extent (host formula only)

typedef float f32x4 __attribute__((ext_vector_type(4)));

// ---------------------------------------------------------------------------
// sc0 ops: agent-scope relaxed (flags, barriers, cross-XCD-visible state).
// ---------------------------------------------------------------------------
__device__ __forceinline__ unsigned ld_u32_sc0(const unsigned* p) {
    return __hip_atomic_load((unsigned*)p, __ATOMIC_RELAXED, __HIP_MEMORY_SCOPE_AGENT);
}
__device__ __forceinline__ void st_u32_sc0(unsigned* p, unsigned v) {
    __hip_atomic_store(p, v, __ATOMIC_RELAXED, __HIP_MEMORY_SCOPE_AGENT);
}

// L1-bypassing (sc0) loads, no internal waitcnt: issue many, wait once.
__device__ __forceinline__ f32x4 ld4_nw(const f32x4* p) {
    f32x4 v;
    asm volatile("global_load_dwordx4 %0, %1, off sc0" : "=v"(v) : "v"(p));
    return v;
}
__device__ __forceinline__ float ld1_l2(const float* p) {
    float v;
    asm volatile("global_load_dword %0, %1, off sc0\n\ts_waitcnt vmcnt(0)"
                 : "=v"(v) : "v"(p) : "memory");
    return v;
}
__device__ __forceinline__ void wait_vm0() {
    asm volatile("s_waitcnt vmcnt(0)" ::: "memory");
    __builtin_amdgcn_sched_barrier(0);
}

__device__ __forceinline__ int get_xcd() {
    unsigned x;
    asm volatile("s_getreg_b32 %0, hwreg(HW_REG_XCC_ID)" : "=s"(x));
    return (int)(x & 7u);
}

// global barrier (R3-proven; prologue / slow path only)
__device__ __forceinline__ void grid_barrier(unsigned* cnt, unsigned* gen,
                                             unsigned target, unsigned nblocks) {
    __syncthreads();
    if (threadIdx.x == 0) {
        __threadfence();
        unsigned arrived = __hip_atomic_fetch_add(cnt, 1u, __ATOMIC_ACQ_REL,
                                                  __HIP_MEMORY_SCOPE_AGENT);
        if (arrived == nblocks - 1u) {
            __hip_atomic_store(cnt, 0u, __ATOMIC_RELAXED, __HIP_MEMORY_SCOPE_AGENT);
            __hip_atomic_fetch_add(gen, 1u, __ATOMIC_RELEASE, __HIP_MEMORY_SCOPE_AGENT);
        } else {
            while (__hip_atomic_load(gen, __ATOMIC_RELAXED,
                                     __HIP_MEMORY_SCOPE_AGENT) < target)
                __builtin_amdgcn_s_sleep(2);
        }
        __threadfence();
    }
    __syncthreads();
}

// XCD-local barrier (R6-proven; no cache maintenance)
__device__ __forceinline__ void xcd_barrier(unsigned* cnt, unsigned* gen,
                                            unsigned target, unsigned nblocks) {
    __syncthreads();
    if (threadIdx.x == 0) {
        unsigned arrived = __hip_atomic_fetch_add(cnt, 1u, __ATOMIC_RELEASE,
                                                  __HIP_MEMORY_SCOPE_WORKGROUP);
        if (arrived == nblocks - 1u) {
            __hip_atomic_store(cnt, 0u, __ATOMIC_RELAXED,
                               __HIP_MEMORY_SCOPE_WORKGROUP);
            __hip_atomic_fetch_add(gen, 1u, __ATOMIC_RELEASE,
                                   __HIP_MEMORY_SCOPE_WORKGROUP);
        } else {
            while (ld_u32_sc0(gen) < target)
                __builtin_amdgcn_s_sleep(2);
        }
    }
    __syncthreads();
}

__device__ __forceinline__ void softmax_row(const float* __restrict__ fp,
                                            const int* __restrict__ adj,
                                            float* __restrict__ wout,
                                            size_t base, int N) {
    const float4* f4 = (const float4*)(fp + base);
    const int4*   a4 = (const int4*)(adj + base);
    float v[DEG];
#pragma unroll
    for (int k = 0; k < DEG / 4; ++k) {
        float4 f = f4[k];
        int4   a = a4[k];
        v[4*k+0] = (a.x == N) ? f.x - 1e7f : f.x;
        v[4*k+1] = (a.y == N) ? f.y - 1e7f : f.y;
        v[4*k+2] = (a.z == N) ? f.z - 1e7f : f.z;
        v[4*k+3] = (a.w == N) ? f.w - 1e7f : f.w;
    }
    float m = v[0];
#pragma unroll
    for (int j = 1; j < DEG; ++j) m = fmaxf(m, v[j]);
    float s = 0.f;
#pragma unroll
    for (int j = 0; j < DEG; ++j) { v[j] = __expf(v[j] - m); s += v[j]; }
    float inv = 1.f / s;
    float4* w4 = (float4*)(wout + base);
#pragma unroll
    for (int k = 0; k < DEG / 4; ++k) {
        float4 o;
        o.x = v[4*k+0] * inv;
        o.y = v[4*k+1] * inv;
        o.z = v[4*k+2] * inv;
        o.w = v[4*k+3] * inv;
        w4[k] = o;
    }
}

// E12 accumulate: 12 gathers from Rc (batch-local indices)
__device__ __forceinline__ float node_acc12(const int* __restrict__ es,
                                            const float* __restrict__ ew,
                                            const float* __restrict__ Rc) {
    const int4*   s4 = (const int4*)es;
    const float4* w4 = (const float4*)ew;
    int4 a = s4[0], b = s4[1], c = s4[2];
    float4 x = w4[0], y = w4[1], z = w4[2];
    float acc;
    acc  = x.x * Rc[a.x];  acc += x.y * Rc[a.y];
    acc += x.z * Rc[a.z];  acc += x.w * Rc[a.w];
    acc += y.x * Rc[b.x];  acc += y.y * Rc[b.y];
    acc += y.z * Rc[b.z];  acc += y.w * Rc[b.w];
    acc += z.x * Rc[c.x];  acc += z.y * Rc[c.y];
    acc += z.z * Rc[c.z];  acc += z.w * Rc[c.w];
    return acc;
}

__device__ __forceinline__ void scale_row(float* __restrict__ wout, int g, float r) {
    float4* w4 = (float4*)(wout + (size_t)g * DEG);
#pragma unroll
    for (int k = 0; k < DEG / 4; ++k) {
        float4 v = w4[k];
        v.x *= r; v.y *= r; v.z *= r; v.w *= r;
        w4[k] = v;
    }
}

// stage helpers: fixed-unroll register staging (compile-time indices only)
__device__ __forceinline__ void stage_issue(const float* src, int ce, int tid,
                                            f32x4* pv) {
    const int n4 = ce >> 2;
    const f32x4* s4 = (const f32x4*)src;
#pragma unroll
    for (int k = 0; k < UST; ++k) {
        int i4 = tid + k * BLK;
        if (i4 < n4) pv[k] = ld4_nw(s4 + i4);
    }
}
__device__ __forceinline__ void stage_write(float* L, const float* src, int ce,
                                            int tid, const f32x4* pv) {
    const int n4 = ce >> 2;
    f32x4* l4 = (f32x4*)L;
#pragma unroll
    for (int k = 0; k < UST; ++k) {
        int i4 = tid + k * BLK;
        if (i4 < n4) l4[i4] = pv[k];
    }
    for (int i = (n4 << 2) + tid; i < ce; i += BLK)
        L[i] = ld1_l2(src + i);
}

// ===========================================================================
// FUSED v12. R1-R5: wall pinned at ~1025us across five variants; the one
// shared, untouched resource was the per-round edge-stream refetch into L2
// (9.6MB/XCD/round > 4MB L2 -> 100% miss every round). v12 ELIMINATES it:
// block-level redistribution makes per-thread per-chunk edge counts uniform
// (K=5 x NCH=8 = 40 slots, ~9% padding); each thread holds its 40 edges in
// REGISTERS (meta u32 + w f32, chunk loop fully unrolled -> static indices);
// accumulation into per-node LDS acc[] via ds_add_f32 atomics. Per round:
// zero stream VMEM -- only L2 R-staging + LDS ops + barriers. Overflow of
// any bucket (>5120) or VGPR-driven launch failure fall back safely.
// ===========================================================================
__global__ __launch_bounds__(BLK, 4)
void fused12_k(const float* __restrict__ fp, const int* __restrict__ adj,
               const int* __restrict__ in_idx, const float* __restrict__ dem,
               const int* __restrict__ nn, float* __restrict__ wout,
               char* __restrict__ wsb, int nodes) {
    __shared__ __align__(16) float lds2[2][LDSH];
    __shared__ float accS[4 * BLK];                 // per-node inflow (16 KB)
    __shared__ int s_bc[NCH];                       // bucket tickets/counts
    __shared__ int s_xcd, s_rank, s_mode, s_part, s_jbad;

    unsigned* g_cnt  = (unsigned*)(wsb);
    unsigned* g_gen  = (unsigned*)(wsb + 128);
    unsigned* blkcnt = (unsigned*)(wsb + 2304);   // [8]
    unsigned* ovf    = (unsigned*)(wsb + 2432);
    unsigned* jovf   = (unsigned*)(wsb + 2436);
    int*   e_src   = (int*)(wsb + 4096);
    float* e_w     = (float*)(wsb + 4096 + (size_t)nodes * E12 * 4);
    float* Rf0     = (float*)((char*)e_w + (size_t)nodes * E12 * 4);
    float* Rf1     = Rf0 + nodes;
    float* slices  = Rf1 + nodes;                   // 16 x N floats
    uint2* regions = (uint2*)((char*)(slices) + (size_t)nodes * 16);

    const int N   = *nn;
    const int tid = (int)threadIdx.x;
    const int T   = (int)gridDim.x * BLK;
    const unsigned nblocks = gridDim.x;
    unsigned gb = 0;

    // ---- entry: self-organize ----
    if (tid == 0) {
        int x = get_xcd();
        s_xcd  = x;
        s_rank = (int)__hip_atomic_fetch_add(&blkcnt[x], 1u, __ATOMIC_RELAXED,
                                             __HIP_MEMORY_SCOPE_AGENT);
    }
    __syncthreads();
    const int my_xcd  = s_xcd;
    const int my_rank = s_rank;

    // ---- P0: softmax (global partition, 2 nodes/thread) ----
#pragma unroll
    for (int rep = 0; rep < 2; ++rep) {
        int g = (int)blockIdx.x * BLK + tid + rep * T;
        if (g < nodes) softmax_row(fp, adj, wout, (size_t)g * DEG, N);
    }
    grid_barrier(g_cnt, g_gen, ++gb, nblocks);

    // ---- P1: E12 compaction + validity checks (global partition) ----
#pragma unroll
    for (int rep = 0; rep < 2; ++rep) {
        int g = (int)blockIdx.x * BLK + tid + rep * T;
        if (g >= nodes) continue;
        const int gbat = g / N;
        const int4* t4 = (const int4*)(in_idx + (size_t)g * 48);
        int cb[16], cs[16], cl[16];
#pragma unroll
        for (int q = 0; q < 4; ++q) {
            int4 qa = t4[3*q + 0];
            int4 qb = t4[3*q + 1];
            int4 qc = t4[3*q + 2];
            cb[4*q+0] = qa.x; cs[4*q+0] = qa.y; cl[4*q+0] = qa.z;
            cb[4*q+1] = qa.w; cs[4*q+1] = qb.x; cl[4*q+1] = qb.y;
            cb[4*q+2] = qb.z; cs[4*q+2] = qb.w; cl[4*q+2] = qc.x;
            cb[4*q+3] = qc.y; cs[4*q+3] = qc.z; cl[4*q+3] = qc.w;
        }
        float cw[16];
#pragma unroll
        for (int k = 0; k < 16; ++k)
            cw[k] = wout[((size_t)cb[k] * N + cs[k]) * DEG + cl[k]];
        bool bad = (cw[12] != 0.f) || (cw[13] != 0.f) ||
                   (cw[14] != 0.f) || (cw[15] != 0.f);
#pragma unroll
        for (int k = 0; k < E12; ++k)
            bad = bad || (cb[k] != gbat) || ((unsigned)cs[k] >= (unsigned)N);
        if (bad) st_u32_sc0(ovf, 1u);
        int4*   es4 = (int4*)(e_src + (size_t)g * E12);
        float4* ew4 = (float4*)(e_w + (size_t)g * E12);
        es4[0] = make_int4(cs[0], cs[1], cs[2], cs[3]);     // batch-LOCAL srcs
        es4[1] = make_int4(cs[4], cs[5], cs[6], cs[7]);
        es4[2] = make_int4(cs[8], cs[9], cs[10], cs[11]);
        ew4[0] = make_float4(cw[0], cw[1], cw[2], cw[3]);
        ew4[1] = make_float4(cw[4], cw[5], cw[6], cw[7]);
        ew4[2] = make_float4(cw[8], cw[9], cw[10], cw[11]);
    }
    grid_barrier(g_cnt, g_gen, ++gb, nblocks);

    // ---- mode decision ----
    const int npb   = (N + 31) >> 5;                     // nodes per rank
    const int chunk = (((N + NCH - 1) / NCH) + 3) & ~3;  // x4-aligned chunk
    if (tid == 0) {
        unsigned cc[8];
#pragma unroll
        for (int x = 0; x < 8; ++x) cc[x] = ld_u32_sc0(&blkcnt[x]);
        bool ok = (4 * N == nodes) && (N > 0) && (N % 4 == 0) &&
                  (npb <= 4 * BLK) && (chunk <= LDSH) &&
                  (ld_u32_sc0(ovf) == 0u);
#pragma unroll
        for (int p = 0; p < 4; ++p)
            ok = ok && (cc[2*p] >= 32u || cc[2*p+1] >= 32u);
        s_mode = ok ? 1 : 0;
        s_part = (ok && cc[my_xcd] >= 32u && my_rank < 32) ? 1 : 0;
    }
    __syncthreads();
    const bool fast = (s_mode == 1);
    const bool part = (s_part == 1);

    if (fast) {
        const int batch = my_xcd >> 1;
        const int lbase = my_rank * npb;
        const int lim   = min(lbase + npb, N);
        float d[4];
        float r[4];
        uint2* reg = regions + (size_t)(my_xcd * 32 + my_rank) * (SLOTS * BLK);

        if (part) {
            if (tid < NCH) s_bc[tid] = 0;
            __syncthreads();
            const int b1 = chunk, b2 = 2*chunk, b3 = 3*chunk, b4 = 4*chunk,
                      b5 = 5*chunk, b6 = 6*chunk, b7 = 7*chunk;
            // pass 1: per-thread per-bucket counts (scalar regs, no dyn idx)
            int c0=0,c1=0,c2=0,c3=0,c4=0,c5=0,c6=0,c7=0;
#pragma unroll
            for (int s = 0; s < 4; ++s) {
                int l = lbase + s * BLK + tid;
                d[s] = 0.f;
                if (l < lim) {
                    int g = batch * N + l;
                    d[s] = dem[g];
                    const int* es = e_src + (size_t)g * E12;
#pragma unroll
                    for (int k = 0; k < E12; ++k) {
                        int src = es[k];
                        int c = (src>=b1)+(src>=b2)+(src>=b3)+(src>=b4)+
                                (src>=b5)+(src>=b6)+(src>=b7);
                        c0 += (c==0); c1 += (c==1); c2 += (c==2); c3 += (c==3);
                        c4 += (c==4); c5 += (c==5); c6 += (c==6); c7 += (c==7);
                    }
                }
            }
            // range reservation: one LDS atomic per bucket per thread
            int u0 = atomicAdd(&s_bc[0], c0);
            int u1 = atomicAdd(&s_bc[1], c1);
            int u2 = atomicAdd(&s_bc[2], c2);
            int u3 = atomicAdd(&s_bc[3], c3);
            int u4 = atomicAdd(&s_bc[4], c4);
            int u5 = atomicAdd(&s_bc[5], c5);
            int u6 = atomicAdd(&s_bc[6], c6);
            int u7 = atomicAdd(&s_bc[7], c7);
            // pass 2: scatter edges to (bucket, position) slots
#pragma unroll
            for (int s = 0; s < 4; ++s) {
                int l = lbase + s * BLK + tid;
                if (l >= lim) continue;
                int g = batch * N + l;
                const int*   es = e_src + (size_t)g * E12;
                const float* ew = e_w + (size_t)g * E12;
                const unsigned tgt = (unsigned)(s * BLK + tid) << 14;
#pragma unroll
                for (int k = 0; k < E12; ++k) {
                    int src = es[k];
                    float w = ew[k];
                    int c = (src>=b1)+(src>=b2)+(src>=b3)+(src>=b4)+
                            (src>=b5)+(src>=b6)+(src>=b7);
                    int p = (c==0)?u0:(c==1)?u1:(c==2)?u2:(c==3)?u3:
                            (c==4)?u4:(c==5)?u5:(c==6)?u6:u7;
                    if (p < KSLOT * BLK) {
                        int kk = p >> 10;            // slot row
                        int ow = p & (BLK - 1);      // owner thread
                        reg[((size_t)(c * KSLOT + kk)) * BLK + ow] =
                            make_uint2((unsigned)(src - c * chunk) | tgt,
                                       __float_as_uint(w));
                    }
                    u0 += (c==0); u1 += (c==1); u2 += (c==2); u3 += (c==3);
                    u4 += (c==4); u5 += (c==5); u6 += (c==6); u7 += (c==7);
                }
            }
            __syncthreads();
            if (tid == 0) {
                bool bad = false;
#pragma unroll
                for (int c = 0; c < NCH; ++c) bad = bad || (s_bc[c] > KSLOT*BLK);
                if (bad) st_u32_sc0(jovf, 1u);
            }
        }
        grid_barrier(g_cnt, g_gen, ++gb, nblocks);   // agree on jovf
        if (tid == 0) s_jbad = (int)ld_u32_sc0(jovf);
        __syncthreads();

        if (s_jbad == 0) {
            if (!part) return;            // extra / deficient-XCD blocks exit
            // ---- load 40 slots into registers; zero acc ----
            unsigned mmeta[SLOTS];
            float    mw[SLOTS];
#pragma unroll
            for (int c = 0; c < NCH; ++c) {
#pragma unroll
                for (int k = 0; k < KSLOT; ++k) {
                    uint2 e = make_uint2(0u, 0u);
                    if (k * BLK + tid < s_bc[c])
                        e = reg[((size_t)(c * KSLOT + k)) * BLK + tid];
                    mmeta[c * KSLOT + k] = e.x;
                    mw[c * KSLOT + k]    = __uint_as_float(e.y);
                }
            }
#pragma unroll
            for (int s = 0; s < 4; ++s) accS[s * BLK + tid] = 0.f;

            // ---- fast rounds: XCD-local, zero per-round VMEM stream ----
            unsigned* xc = (unsigned*)(wsb + 256 + my_xcd * 256);
            unsigned* xg = (unsigned*)(wsb + 256 + my_xcd * 256 + 128);
            unsigned xb = 0;
            float* bufA = slices + (size_t)(2 * my_xcd + 0) * N;
            float* bufB = slices + (size_t)(2 * my_xcd + 1) * N;

#pragma unroll
            for (int s = 0; s < 4; ++s) {
                int l = lbase + s * BLK + tid;
                r[s] = fmaxf(-d[s], 0.f);
                if (l < lim) bufA[l] = r[s];
            }
            xcd_barrier(xc, xg, ++xb, 32u);

            float* Rin  = bufA;
            float* Rout = bufB;

            for (int t = 1; t < MAX_ITERS; ++t) {
                f32x4 pv[UST];
                // stage chunk 0 (the only exposed staging latency per round)
                {
                    const int ce0 = min(chunk, N);
                    stage_issue(Rin, ce0, tid, pv);
                    wait_vm0();
                    stage_write(lds2[0], Rin, ce0, tid, pv);
                }
                __syncthreads();
#pragma unroll
                for (int c = 0; c < NCH; ++c) {
                    const float* L = lds2[c & 1];
                    if (c + 1 < NCH) {
                        const float* src1 = Rin + (c + 1) * chunk;
                        const int ce1 = min(chunk, N - (c + 1) * chunk);
                        stage_issue(src1, ce1, tid, pv);
                        // consume chunk c: 5 register slots -> LDS atomics
#pragma unroll
                        for (int k = 0; k < KSLOT; ++k) {
                            unsigned m = mmeta[c * KSLOT + k];
                            float    w = mw[c * KSLOT + k];
                            float   Rv = L[m & 16383u];
                            atomicAdd(&accS[m >> 14], w * Rv);
                        }
                        wait_vm0();
                        stage_write((float*)lds2[(c + 1) & 1], src1, ce1, tid, pv);
                    } else {
#pragma unroll
                        for (int k = 0; k < KSLOT; ++k) {
                            unsigned m = mmeta[c * KSLOT + k];
                            float    w = mw[c * KSLOT + k];
                            float   Rv = L[m & 16383u];
                            atomicAdd(&accS[m >> 14], w * Rv);
                        }
                    }
                    __syncthreads();
                }
                // per-round epilogue: each thread reads+zeroes its own slots
#pragma unroll
                for (int s = 0; s < 4; ++s) {
                    float a = accS[s * BLK + tid];
                    accS[s * BLK + tid] = 0.f;
                    r[s] = fmaxf(a - d[s], 0.f);
                }
                if (t < MAX_ITERS - 1) {
#pragma unroll
                    for (int s = 0; s < 4; ++s) {
                        int l = lbase + s * BLK + tid;
                        if (l < lim) Rout[l] = r[s];
                    }
                    xcd_barrier(xc, xg, ++xb, 32u);
                    float* tmp = Rin; Rin = Rout; Rout = tmp;
                }
            }
#pragma unroll
            for (int s = 0; s < 4; ++s) {
                int l = lbase + s * BLK + tid;
                if (l < lim) scale_row(wout, batch * N + l, r[s]);
            }
            return;
        }
        // fall through to slow rounds (all blocks; bucket overflow)
    }

    // ---- SLOW rounds: E12 direct gathers + global barriers ----
    {
        int g0 = (int)blockIdx.x * BLK + tid;
        int g1 = g0 + T;
        bool a0 = (g0 < nodes), a1 = (g1 < nodes);
        float d0 = a0 ? dem[g0] : 0.f;
        float d1 = a1 ? dem[g1] : 0.f;
        int base0 = a0 ? (g0 / N) * N : 0;
        int base1 = a1 ? (g1 / N) * N : 0;
        float r0 = fmaxf(-d0, 0.f), r1 = fmaxf(-d1, 0.f);
        if (a0) Rf0[g0] = r0;
        if (a1) Rf0[g1] = r1;
        grid_barrier(g_cnt, g_gen, ++gb, nblocks);
        const float* Rc = Rf0;
        float*       Rn = Rf1;
        for (int t = 1; t < MAX_ITERS; ++t) {
            if (a0) r0 = fmaxf(node_acc12(e_src + (size_t)g0 * E12,
                                          e_w + (size_t)g0 * E12,
                                          Rc + base0) - d0, 0.f);
            if (a1) r1 = fmaxf(node_acc12(e_src + (size_t)g1 * E12,
                                          e_w + (size_t)g1 * E12,
                                          Rc + base1) - d1, 0.f);
            if (t < MAX_ITERS - 1) {
                if (a0) Rn[g0] = r0;
                if (a1) Rn[g1] = r1;
                grid_barrier(g_cnt, g_gen, ++gb, nblocks);
                float* tmp = (float*)Rc; Rc = Rn; Rn = tmp;
            }
        }
        if (a0) scale_row(wout, g0, r0);
        if (a1) scale_row(wout, g1, r1);
    }
}

// ===========================================================================
// HOST FALLBACK (round-1 kernels, known-correct)
// ===========================================================================
__global__ void softmax_k(const float* __restrict__ fp, const int* __restrict__ adj,
                          const int* __restrict__ nn, float* __restrict__ wout,
                          int nodes) {
    int i = blockIdx.x * blockDim.x + threadIdx.x;
    if (i >= nodes) return;
    softmax_row(fp, adj, wout, (size_t)i * DEG, *nn);
}

__global__ void gather_k(const int* __restrict__ in_idx, const float* __restrict__ w,
                         const int* __restrict__ nn, int* __restrict__ e_srcO,
                         float* __restrict__ e_wO, int edges) {
    int e = blockIdx.x * blockDim.x + threadIdx.x;
    if (e >= edges) return;
    const int N = *nn;
    size_t e3 = 3 * (size_t)e;
    int fi = in_idx[e3] * N + in_idx[e3 + 1];
    e_srcO[e] = fi;
    e_wO[e]   = w[(size_t)fi * DEG + in_idx[e3 + 2]];
}

__global__ void iter_k(const int* __restrict__ e_srcO, const float* __restrict__ e_wO,
                       const float* __restrict__ dem, const float* __restrict__ Rin,
                       float* __restrict__ Rout, int nodes) {
    int i = blockIdx.x * blockDim.x + threadIdx.x;
    if (i >= nodes) return;
    const size_t base = (size_t)i * DEG;
    const int4*   s4 = (const int4*)(e_srcO + base);
    const float4* w4 = (const float4*)(e_wO + base);
    float acc = 0.f;
#pragma unroll
    for (int k = 0; k < DEG / 4; ++k) {
        int4   s = s4[k];
        float4 w = w4[k];
        acc += w.x * Rin[s.x];
        acc += w.y * Rin[s.y];
        acc += w.z * Rin[s.z];
        acc += w.w * Rin[s.w];
    }
    float r = acc - dem[i];
    Rout[i] = r > 0.f ? r : 0.f;
}

__global__ void final_k(const float* __restrict__ w, const float* __restrict__ R,
                        float* __restrict__ out, int nodes) {
    int i = blockIdx.x * blockDim.x + threadIdx.x;
    if (i >= nodes) return;
    scale_row((float*)w, i, R[i]);
    (void)out;
}

extern "C" void kernel_launch(void* const* d_in, const int* in_sizes, int n_in,
                              void* d_out, int out_size, void* d_ws, size_t ws_size,
                              hipStream_t stream) {
    const float* fp  = (const float*)d_in[0];
    const float* dem = (const float*)d_in[1];
    const int*   adj = (const int*)d_in[2];
    const int*   idx = (const int*)d_in[3];
    const int*   nn  = (const int*)d_in[4];

    const int edges = in_sizes[0];   // B*N*D
    const int nodes = in_sizes[1];   // B*N

    float* weights = (float*)d_out;
    char*  ws      = (char*)d_ws;

    int dev = 0, cus = 0, maxBlk = 0;
    hipGetDevice(&dev);
    hipDeviceGetAttribute(&cus, hipDeviceAttributeMultiprocessorCount, dev);
    hipOccupancyMaxActiveBlocksPerMultiprocessor(&maxBlk, (const void*)fused12_k,
                                                 BLK, 0);

    // ws layout: 4096 | e_src 12n*4 | e_w 12n*4 | Rf 2n*4 | slices 16n | regions
    const size_t need = 4096 + (size_t)nodes * (E12 * 8 + 8 + 16)
                      + (size_t)256 * JMAX * BLK * 8;
    const int grid = cus;

    const bool fused_ok = (maxBlk >= 1) && (cus >= 16) &&
                          ((long long)grid * BLK * 2 >= nodes) &&
                          (ws_size >= need) && (nodes % 4 == 0);

    if (fused_ok) {
        hipMemsetAsync(ws, 0, 4096, stream);
        void* args[] = { (void*)&fp, (void*)&adj, (void*)&idx, (void*)&dem,
                         (void*)&nn, (void*)&weights, (void*)&ws, (void*)&nodes };
        hipLaunchCooperativeKernel((const void*)fused12_k, dim3(grid), dim3(BLK),
                                   args, 0, stream);
    } else {
        int*   e_srcO = (int*)ws;
        float* e_wO   = (float*)(ws + (size_t)edges * sizeof(int));
        float* R0     = (float*)(ws + (size_t)edges * 8);
        float* R1     = R0 + nodes;
        const int blk = 256;
        const int gn = (nodes + blk - 1) / blk;
        const int ge = (edges + blk - 1) / blk;
        hipMemsetAsync(R0, 0, (size_t)nodes * sizeof(float), stream);
        softmax_k<<<gn, blk, 0, stream>>>(fp, adj, nn, weights, nodes);
        gather_k<<<ge, blk, 0, stream>>>(idx, weights, nn, e_srcO, e_wO, edges);
        float* a = R0;
        float* b = R1;
        for (int t = 0; t < MAX_ITERS; ++t) {
            iter_k<<<gn, blk, 0, stream>>>(e_srcO, e_wO, dem, a, b, nodes);
            float* tmp = a; a = b; b = tmp;
        }
        final_k<<<gn, blk, 0, stream>>>(weights, a, (float*)d_out, nodes);
    }
}